// Round 1
// baseline (2500.162 us; speedup 1.0000x reference)
//
#include <hip/hip_runtime.h>

#define PI_D 3.14159265358979323846

constexpr int S_L20 = 12341;  // sum_{l<=20} (2l+1)^2
constexpr int S_L10 = 1771;
constexpr int S_L5  = 286;
constexpr int C_L20 = 441;    // (20+1)^2

__host__ __device__ __forceinline__ int loff(int l) { return l*(4*l*l-1)/3; }

__device__ __forceinline__ int isqrt_dev(int c) {
  int l = (int)sqrtf((float)c);
  while ((l+1)*(l+1) <= c) ++l;
  while (l*l > c) --l;
  return l;
}

// small Wigner-d d^l_{mp,m}(beta); cpw/spw are power tables of cos(beta/2), sin(beta/2)
__device__ double d_small(int l, int mp, int m, const double* cpw, const double* spw, const double* fact) {
  double pref = sqrt(fact[l+mp]*fact[l-mp]*fact[l+m]*fact[l-m]);
  int k0 = max(0, m-mp), k1 = min(l+m, l-mp);
  double val = 0.0;
  for (int k = k0; k <= k1; ++k) {
    double den = fact[l+m-k]*fact[k]*fact[mp-m+k]*fact[l-mp-k];
    double t = (pref/den)*cpw[2*l+m-mp-2*k]*spw[mp-m+2*k];
    val += ((mp-m+k)&1) ? -t : t;
  }
  return val;
}

// real-basis Wigner-d element, row ap, col bp (signed, in [-l,l]).
// Derived from U d U^H with U the complex->real SH change of basis.
__device__ double dr_elem(int l, int ap, int bp, const double* cpw, const double* spw, const double* fact) {
  const double IR2 = 0.70710678118654752440;
  if (ap == 0 && bp == 0) return d_small(l,0,0,cpw,spw,fact);
  if (bp == 0) {
    if (ap < 0) return 0.0;
    double sp = (ap&1)? -1.0: 1.0;
    return IR2*(d_small(l,-ap,0,cpw,spw,fact) + sp*d_small(l,ap,0,cpw,spw,fact));
  }
  if (ap == 0) {
    if (bp < 0) return 0.0;
    double sm = (bp&1)? -1.0: 1.0;
    return IR2*(d_small(l,0,-bp,cpw,spw,fact) + sm*d_small(l,0,bp,cpw,spw,fact));
  }
  if (ap > 0 && bp > 0) {
    double sp = (ap&1)?-1.0:1.0, sm = (bp&1)?-1.0:1.0;
    return 0.5*(d_small(l,-ap,-bp,cpw,spw,fact) + sm*d_small(l,-ap,bp,cpw,spw,fact)
              + sp*d_small(l,ap,-bp,cpw,spw,fact) + sp*sm*d_small(l,ap,bp,cpw,spw,fact));
  }
  if (ap < 0 && bp < 0) {
    int mp = -ap, m = -bp;
    double sp = (mp&1)?-1.0:1.0, sm = (m&1)?-1.0:1.0;
    return 0.5*(d_small(l,-mp,-m,cpw,spw,fact) - sm*d_small(l,-mp,m,cpw,spw,fact)
              - sp*d_small(l,mp,-m,cpw,spw,fact) + sp*sm*d_small(l,mp,m,cpw,spw,fact));
  }
  return 0.0;
}

// beta of point p: mode 0: (p+0.5)*pi/gridn ; mode 1: so3 near-identity ; mode 2: s2 near-identity
__device__ double beta_of(int mode, int p, int gridn) {
  if (mode == 0) return (p + 0.5) * (PI_D / gridn);
  if (mode == 1) return (double)(((p >> 3) % 3) + 1) * (PI_D / 24.0);
  return (double)((p % 3) + 1) * (PI_D / 24.0);
}

#define INIT_TABLES(mode, gridn) \
  __shared__ double cpw[44], spw[44], fact[44]; \
  { double beta_ = beta_of(mode, (int)blockIdx.y, gridn); \
    if (threadIdx.x == 0) { double cb_ = cos(beta_*0.5), sb_ = sin(beta_*0.5); \
      cpw[0]=1.0; spw[0]=1.0; fact[0]=1.0; \
      for (int i_=1;i_<44;++i_){cpw[i_]=cpw[i_-1]*cb_; spw[i_]=spw[i_-1]*sb_; fact[i_]=fact[i_-1]*(double)i_;} } \
    __syncthreads(); }

// full real Wigner-d table for one beta set, PRE-SCALED by sqrt(2l+1). out[p][S]
__global__ __launch_bounds__(256) void k_drfull(float* out, int lmax, int S, int mode, int gridn) {
  INIT_TABLES(mode, gridn);
  int p = blockIdx.y;
  int base = blockIdx.x*1024;
  int end = min(S, base + 1024);
  for (int t = base + (int)threadIdx.x; t < end; t += 256) {
    int l = 0; while (l < lmax && t >= loff(l+1)) ++l;
    int j = t - loff(l), d = 2*l+1;
    int a = j/d, b = j%d;
    double v = dr_elem(l, a-l, b-l, cpw, spw, fact) * sqrt(2.0*l+1.0);
    out[(size_t)p*S + t] = (float)v;
  }
}

// m=0 column of real Wigner-d (for spherical harmonics), PRE-SCALED by sqrt(2l+1). out[p][(lmax+1)^2]
__global__ __launch_bounds__(256) void k_drc(float* out, int lmax, int mode, int gridn) {
  INIT_TABLES(mode, gridn);
  int p = blockIdx.y;
  int C = (lmax+1)*(lmax+1);
  for (int t = threadIdx.x; t < C; t += 256) {
    int l = isqrt_dev(t);
    int u = t - l*l - l;
    double v;
    if (u < 0) v = 0.0;
    else if (u == 0) v = d_small(l,0,0,cpw,spw,fact);
    else {
      double sp = (u&1)? -1.0: 1.0;
      v = 0.70710678118654752440*(d_small(l,-u,0,cpw,spw,fact) + sp*d_small(l,u,0,cpw,spw,fact));
    }
    out[(size_t)p*C + t] = (float)(v * sqrt(2.0*l+1.0));
  }
}

// FROM_S2 in x-natural layout: FS2[(ia*60+ib)][c] = qw(ib) * sqrt(2l+1)*(cos(u a)*drc[u] + sin(u a)*drc[-u])
__global__ __launch_bounds__(256) void k_fs2(const float* __restrict__ drc, float* __restrict__ FS2) {
  int e = blockIdx.x*256 + threadIdx.x;
  if (e >= 3600*441) return;
  int k = e / 441, c = e % 441;
  int ia = k / 60, ib = k % 60;
  int l = isqrt_dev(c);
  int u = c - l*l - l;
  double alpha = (double)ia*(2.0*PI_D/60.0);
  double beta  = ((double)ib + 0.5)*(PI_D/60.0);
  double drp = (double)drc[ib*441 + c];
  double drn = (double)drc[ib*441 + (c - 2*u)];
  double val = cos((double)u*alpha)*drp + sin((double)u*alpha)*drn;
  FS2[e] = (float)(val * (sin(beta)*PI_D/(2.0*60.0*60.0)));
}

// psi1[o][c] = (1/sqrt24) * sum_p Y_K[p,c] * w1[o,p]
__global__ __launch_bounds__(256) void k_psi1(const float* __restrict__ drc24, const float* __restrict__ w1,
                                              float* __restrict__ psi1) {
  int e = blockIdx.x*256 + threadIdx.x;
  if (e >= 64*441) return;
  int o = e / 441, c = e % 441;
  int l = isqrt_dev(c);
  int u = c - l*l - l;
  float acc = 0.f;
  for (int p = 0; p < 24; ++p) {
    double alpha = (double)(p/3)*(PI_D/4.0);
    double y = cos((double)u*alpha)*(double)drc24[p*441+c] + sin((double)u*alpha)*(double)drc24[p*441 + (c-2*u)];
    acc += (float)y * w1[o*24 + p];
  }
  psi1[e] = acc * 0.20412414523193150818f;
}

// D_K (flat wigner at near-identity so3 points) from pre-scaled dr table
__global__ __launch_bounds__(256) void k_dk(const float* __restrict__ drk, float* __restrict__ DK, int S, int lmax) {
  int e = blockIdx.x*256 + threadIdx.x;
  if (e >= 168*S) return;
  int n = e / S, idx = e % S;
  int l = 0; while (l < lmax && idx >= loff(l+1)) ++l;
  int j = idx - loff(l), d = 2*l+1;
  int iu = j/d, im = j%d;
  int u = iu - l, m = im - l;
  int i3 = n/24, k3 = n%8;
  double alpha = (double)i3*(2.0*PI_D/7.0);
  double gamma = (-2.0*PI_D + (double)k3*(4.0*PI_D/7.0)) - alpha;
  const float* drb = drk + (size_t)n*S + loff(l);
  double d_um   = drb[iu*d+im];
  double d_umn  = drb[iu*d + (d-1-im)];
  double d_unm  = drb[(d-1-iu)*d + im];
  double d_unmn = drb[(d-1-iu)*d + (d-1-im)];
  double cA = cos((double)u*alpha), sA = sin((double)u*alpha);
  double cG = cos((double)m*gamma), sG = sin((double)m*gamma);
  DK[e] = (float)(cA*(cG*d_um - sG*d_umn) + sA*(cG*d_unm - sG*d_unmn));
}

// generic strided fp32 GEMM: C[M][N] = alpha * A(r,k) B(k,c); A addr r*ars+k*aks; B addr k*bks+c*bcs
__global__ __launch_bounds__(256) void k_gemm(const float* __restrict__ A, const float* __restrict__ B,
                                              float* __restrict__ C, int M, int N, int K,
                                              long long ars, long long aks, long long bks, long long bcs,
                                              float alpha) {
  __shared__ float As[16][65], Bs[16][65];
  int tm = blockIdx.x*64, tn = blockIdx.y*64;
  int tid = threadIdx.x, ty = tid/16, tx = tid%16;
  float acc[4][4] = {};
  for (int k0 = 0; k0 < K; k0 += 16) {
    for (int t = tid; t < 1024; t += 256) {
      int rr = t % 64, kk = t / 64;
      int r = tm + rr, k = k0 + kk;
      float v = 0.f;
      if (r < M && k < K) v = A[(long long)r*ars + (long long)k*aks];
      As[kk][rr] = v;
    }
    for (int t = tid; t < 1024; t += 256) {
      int cc = t % 64, kk = t / 64;
      int c = tn + cc, k = k0 + kk;
      float v = 0.f;
      if (c < N && k < K) v = B[(long long)k*bks + (long long)c*bcs];
      Bs[kk][cc] = v;
    }
    __syncthreads();
#pragma unroll
    for (int kk = 0; kk < 16; ++kk) {
      float av[4], bv[4];
#pragma unroll
      for (int q = 0; q < 4; ++q) { av[q] = As[kk][ty*4+q]; bv[q] = Bs[kk][tx*4+q]; }
#pragma unroll
      for (int q = 0; q < 4; ++q)
#pragma unroll
        for (int r2 = 0; r2 < 4; ++r2) acc[q][r2] += av[q]*bv[r2];
    }
    __syncthreads();
  }
  for (int q = 0; q < 4; ++q) {
    int r = tm + ty*4 + q; if (r >= M) continue;
    for (int r2 = 0; r2 < 4; ++r2) {
      int c = tn + tx*4 + r2; if (c >= N) continue;
      C[(size_t)r*N + c] = alpha*acc[q][r2];
    }
  }
}

// per-l block linear: out[b,o,l,v,m] = 1/sqrt(FI*d) * sum_{i,u} hin[b,i,l,u,m] * psiT[(i*FO+o)][l,u,v]
__global__ __launch_bounds__(256) void k_lin(const float* __restrict__ hin, const float* __restrict__ psiT,
                                             float* __restrict__ hout, int FI, int FO, int S) {
  int l = blockIdx.z;
  int d = 2*l+1, off = loff(l);
  int Ml = 8*d, Nl = FO*d, Kl = FI*d;
  int tm = blockIdx.x*64, tn = blockIdx.y*64;
  if (tm >= Ml || tn >= Nl) return;
  float alpha = 1.0f/sqrtf((float)(FI*d));
  __shared__ float As[16][65], Bs[16][65];
  int tid = threadIdx.x, ty = tid/16, tx = tid%16;
  float acc[4][4] = {};
  for (int k0 = 0; k0 < Kl; k0 += 16) {
    for (int t = tid; t < 1024; t += 256) {
      int rr = t % 64, kk = t / 64;
      int r = tm + rr, k = k0 + kk;
      float v = 0.f;
      if (r < Ml && k < Kl) {
        int bb = r / d, m = r - bb*d;
        int i  = k / d, u = k - i*d;
        v = hin[((size_t)(bb*FI + i))*S + off + u*d + m];
      }
      As[kk][rr] = v;
    }
    for (int t = tid; t < 1024; t += 256) {
      int cc = t % 64, kk = t / 64;
      int c = tn + cc, k = k0 + kk;
      float v = 0.f;
      if (c < Nl && k < Kl) {
        int o = c / d, vv = c - o*d;
        int i = k / d, u  = k - i*d;
        v = psiT[((size_t)(i*FO + o))*S + off + u*d + vv];
      }
      Bs[kk][cc] = v;
    }
    __syncthreads();
#pragma unroll
    for (int kk = 0; kk < 16; ++kk) {
      float av[4], bv[4];
#pragma unroll
      for (int q = 0; q < 4; ++q) { av[q] = As[kk][ty*4+q]; bv[q] = Bs[kk][tx*4+q]; }
#pragma unroll
      for (int q = 0; q < 4; ++q)
#pragma unroll
        for (int r2 = 0; r2 < 4; ++r2) acc[q][r2] += av[q]*bv[r2];
    }
    __syncthreads();
  }
  for (int q = 0; q < 4; ++q) {
    int r = tm + ty*4 + q; if (r >= Ml) continue;
    int bb = r / d, m = r - bb*d;
    for (int r2 = 0; r2 < 4; ++r2) {
      int c = tn + tx*4 + r2; if (c >= Nl) continue;
      int o = c / d, vv = c - o*d;
      hout[((size_t)(bb*FO + o))*S + off + vv*d + m] = alpha*acc[q][r2];
    }
  }
}

// factorized SO(3) grid synthesis + relu + quad-weight. fw[b][f][ib][ia][ig]
// P[u,m]=sum_l dr~*h(u,m); Q1:h(u,-m); Q2:h(-u,m); Q3:h(-u,-m)  (dr~ pre-scaled sqrt(2l+1))
// f = sum_u cA*(sum_m cG*P + sG*Q1) - sA*(sum_m cG*Q2 + sG*Q3)
template<int L, int NG, bool RANK1, int F>
__global__ __launch_bounds__(256) void k_syn(const float* __restrict__ hin, const float* __restrict__ coeff,
                                             const float* __restrict__ drg, float* __restrict__ fw) {
  constexpr int U = 2*L+1;
  constexpr int S = (L+1)*(2*L+1)*(2*L+3)/3;
  constexpr int HSZ = RANK1 ? 2*C_L20 : S;
  __shared__ float P[U*U], Q1[U*U], Q2[U*U], Q3[U*U];
  __shared__ float Rc[U*NG], Rs[U*NG];
  __shared__ float cg[NG*U], sg[NG*U];
  __shared__ float hrow[HSZ];
  int ib = blockIdx.x, f = blockIdx.y, b = blockIdx.z;
  int tid = threadIdx.x;
  if (RANK1) {
    for (int t = tid; t < C_L20; t += 256) {
      hrow[t]          = hin[f*C_L20 + t];     // psi1 row (u-dependence)
      hrow[C_L20 + t]  = coeff[b*C_L20 + t];   // coeff row (m-dependence)
    }
  } else {
    for (int t = tid; t < S; t += 256) hrow[t] = hin[((size_t)b*F + f)*S + t];
  }
  for (int t = tid; t < NG*U; t += 256) {
    int ig = t / U, mu = t % U - L;
    double ang = (double)mu * (double)ig * (2.0*PI_D/(double)NG);
    cg[t] = (float)cos(ang); sg[t] = (float)sin(ang);
  }
  __syncthreads();
  for (int t = tid; t < U*U; t += 256) {
    int uu = t / U, mm = t % U;
    int au = (uu >= L) ? uu - L : L - uu;
    int am = (mm >= L) ? mm - L : L - mm;
    int lmin = max(au, am);
    float p = 0.f, q1 = 0.f, q2 = 0.f, q3 = 0.f;
    for (int l = lmin; l <= L; ++l) {
      int d = 2*l+1;
      int iu = uu - (L - l), im = mm - (L - l);
      float drv = drg[(size_t)ib*S + loff(l) + iu*d + im];
      if (RANK1) {
        int cb = l*l;
        float hu  = hrow[cb + iu],          hun = hrow[cb + (d-1-iu)];
        float hm  = hrow[C_L20 + cb + im],  hmn = hrow[C_L20 + cb + (d-1-im)];
        p  += drv*hu*hm;  q1 += drv*hu*hmn;  q2 += drv*hun*hm;  q3 += drv*hun*hmn;
      } else {
        int o = loff(l);
        p  += drv*hrow[o + iu*d + im];
        q1 += drv*hrow[o + iu*d + (d-1-im)];
        q2 += drv*hrow[o + (d-1-iu)*d + im];
        q3 += drv*hrow[o + (d-1-iu)*d + (d-1-im)];
      }
    }
    P[t]=p; Q1[t]=q1; Q2[t]=q2; Q3[t]=q3;
  }
  __syncthreads();
  for (int t = tid; t < U*NG; t += 256) {
    int uu = t / NG, ig = t % NG;
    float rc = 0.f, rs = 0.f;
    for (int mm = 0; mm < U; ++mm) {
      float c = cg[ig*U+mm], s = sg[ig*U+mm];
      int pi = uu*U+mm;
      rc += c*P[pi]  + s*Q1[pi];
      rs += c*Q2[pi] + s*Q3[pi];
    }
    Rc[t]=rc; Rs[t]=rs;
  }
  __syncthreads();
  double beta = ((double)ib + 0.5) * (PI_D / (double)NG);
  float qwv = (float)(sin(beta) * PI_D / (2.0*(double)NG*(double)NG*(double)NG));
  size_t obase = (((size_t)b*F + f)*NG + ib)*(size_t)(NG*NG);
  for (int t = tid; t < NG*NG; t += 256) {
    int ia = t / NG, ig = t % NG;
    float acc = 0.f;
    for (int uu = 0; uu < U; ++uu)
      acc += cg[ia*U+uu]*Rc[uu*NG+ig] - sg[ia*U+uu]*Rs[uu*NG+ig];
    fw[obase + t] = fmaxf(acc, 0.0f) * qwv;
  }
}

// factorized SO(3) grid analysis to lmax LO. hout[b][f][SO]
template<int LO, int NG, int F>
__global__ __launch_bounds__(256) void k_ana(const float* __restrict__ fw, const float* __restrict__ drg,
                                             float* __restrict__ hout) {
  constexpr int UO = 2*LO+1;
  constexpr int SO = (LO+1)*(2*LO+1)*(2*LO+3)/3;
  __shared__ float hacc[SO];
  __shared__ float fws[NG*NG];
  __shared__ float Fc[UO*NG], Fs[UO*NG];
  __shared__ float Gcc[UO*UO], Gcs[UO*UO], Gsc[UO*UO], Gss[UO*UO];
  __shared__ float cg[NG*UO], sg[NG*UO];
  int f = blockIdx.x, b = blockIdx.y, tid = threadIdx.x;
  for (int t = tid; t < SO; t += 256) hacc[t] = 0.0f;
  for (int t = tid; t < NG*UO; t += 256) {
    int ig = t / UO, mu = t % UO - LO;
    double ang = (double)mu * (double)ig * (2.0*PI_D/(double)NG);
    cg[t] = (float)cos(ang); sg[t] = (float)sin(ang);
  }
  __syncthreads();
  for (int ib = 0; ib < NG; ++ib) {
    size_t base = (((size_t)b*F + f)*NG + ib)*(size_t)(NG*NG);
    for (int t = tid; t < NG*NG; t += 256) fws[t] = fw[base + t];
    __syncthreads();
    for (int t = tid; t < UO*NG; t += 256) {
      int uu = t / NG, ig = t % NG;
      float fc = 0.f, fs = 0.f;
      for (int ia = 0; ia < NG; ++ia) {
        float v = fws[ia*NG + ig];
        fc += cg[ia*UO + uu]*v;
        fs += sg[ia*UO + uu]*v;
      }
      Fc[t]=fc; Fs[t]=fs;
    }
    __syncthreads();
    for (int t = tid; t < UO*UO; t += 256) {
      int uu = t/UO, mm = t%UO;
      float gcc=0.f,gcs=0.f,gsc=0.f,gss=0.f;
      for (int ig = 0; ig < NG; ++ig) {
        float c = cg[ig*UO+mm], s = sg[ig*UO+mm];
        float fc = Fc[uu*NG+ig], fs = Fs[uu*NG+ig];
        gcc += c*fc; gcs += s*fc; gsc += c*fs; gss += s*fs;
      }
      Gcc[t]=gcc; Gcs[t]=gcs; Gsc[t]=gsc; Gss[t]=gss;
    }
    __syncthreads();
    for (int t = tid; t < SO; t += 256) {
      int l = 0; while (l < LO && t >= loff(l+1)) ++l;
      int j = t - loff(l), d = 2*l+1;
      int iu = j / d, im = j % d;
      int uu = iu + (LO - l), mm = im + (LO - l);
      const float* drb = drg + (size_t)ib*SO + loff(l);
      hacc[t] += Gcc[uu*UO+mm]*drb[iu*d+im]
               - Gcs[uu*UO+mm]*drb[iu*d+(d-1-im)]
               + Gsc[uu*UO+mm]*drb[(d-1-iu)*d+im]
               - Gss[uu*UO+mm]*drb[(d-1-iu)*d+(d-1-im)];
    }
    __syncthreads();
  }
  for (int t = tid; t < SO; t += 256) hout[((size_t)b*F + f)*SO + t] = hacc[t];
}

// final two FC layers. one block, 1024 threads.
__global__ __launch_bounds__(1024) void k_fc(const float* __restrict__ h4, const float* __restrict__ w1,
                                             const float* __restrict__ b1, const float* __restrict__ w2,
                                             const float* __restrict__ b2, float* __restrict__ out) {
  __shared__ float t1[1024];
  int tid = threadIdx.x;
  {
    int b = tid >> 7, j = tid & 127;
    float a = b1[j];
    const float* hr = h4 + b*256;
    for (int k = 0; k < 256; ++k) a += hr[k]*w1[k*128 + j];
    t1[tid] = fmaxf(a, 0.f);
  }
  __syncthreads();
  if (tid < 80) {
    int b = tid / 10, j = tid % 10;
    float a = b2[j];
    for (int k = 0; k < 128; ++k) a += t1[b*128 + k]*w2[k*10 + j];
    out[b*10 + j] = a;
  }
}

extern "C" void kernel_launch(void* const* d_in, const int* in_sizes, int n_in,
                              void* d_out, int out_size, void* d_ws, size_t ws_size,
                              hipStream_t stream) {
  const float* x    = (const float*)d_in[0];
  const float* w1   = (const float*)d_in[1];
  const float* w2   = (const float*)d_in[2];
  const float* w3   = (const float*)d_in[3];
  const float* fcw1 = (const float*)d_in[4];
  const float* fcb1 = (const float*)d_in[5];
  const float* fcw2 = (const float*)d_in[6];
  const float* fcb2 = (const float*)d_in[7];
  float* out = (float*)d_out;

  float* base = (float*)d_ws;
  size_t off = 0;
  auto alloc = [&](size_t n) -> float* { float* p = base + off; off += (n + 63) & ~(size_t)63; return p; };

  float* drc60  = alloc((size_t)60*441);
  float* drc24  = alloc((size_t)24*441);
  float* fs2    = alloc((size_t)3600*441);
  float* psi1   = alloc((size_t)64*441);
  float* coeff  = alloc((size_t)8*441);
  float* drK2   = alloc((size_t)168*S_L10);
  float* drK3   = alloc((size_t)168*S_L5);
  float* dk2    = alloc((size_t)168*S_L10);
  float* dk3    = alloc((size_t)168*S_L5);
  float* psi2T  = alloc((size_t)8192*S_L10);
  float* psi3T  = alloc((size_t)32768*S_L5);
  float* dr20g1 = alloc((size_t)20*S_L20);
  float* dr10g1 = alloc((size_t)20*S_L10);
  float* dr10g2 = alloc((size_t)10*S_L10);
  float* dr5g2  = alloc((size_t)10*S_L5);
  float* dr5g3  = alloc((size_t)6*S_L5);
  float* dr0g3  = alloc(6);
  float* fw1b   = alloc((size_t)8*64*8000);
  float* h2     = alloc((size_t)8*64*S_L10);
  float* h2b    = alloc((size_t)8*128*S_L10);
  float* fw2b   = alloc((size_t)8*128*1000);
  float* h3     = alloc((size_t)8*128*S_L5);
  float* h3b    = alloc((size_t)8*256*S_L5);
  float* fw3b   = alloc((size_t)8*256*216);
  float* h4     = alloc((size_t)8*256);
  if (off * sizeof(float) > ws_size) return;  // insufficient scratch -> fail visibly

  const float inv_s168 = 0.07715167498104595f;  // 1/sqrt(168)

  // ---- constant-table generation (device, fp64, every call: graph-replay safe) ----
  k_drc<<<dim3(1,60), 256, 0, stream>>>(drc60, 20, 0, 60);
  k_drc<<<dim3(1,24), 256, 0, stream>>>(drc24, 20, 2, 0);
  k_drfull<<<dim3((S_L10+1023)/1024,168), 256, 0, stream>>>(drK2, 10, S_L10, 1, 0);
  k_drfull<<<dim3(1,168),                 256, 0, stream>>>(drK3,  5, S_L5,  1, 0);
  k_drfull<<<dim3((S_L20+1023)/1024,20),  256, 0, stream>>>(dr20g1, 20, S_L20, 0, 20);
  k_drfull<<<dim3((S_L10+1023)/1024,20),  256, 0, stream>>>(dr10g1, 10, S_L10, 0, 20);
  k_drfull<<<dim3((S_L10+1023)/1024,10),  256, 0, stream>>>(dr10g2, 10, S_L10, 0, 10);
  k_drfull<<<dim3(1,10), 256, 0, stream>>>(dr5g2, 5, S_L5, 0, 10);
  k_drfull<<<dim3(1,6),  256, 0, stream>>>(dr5g3, 5, S_L5, 0, 6);
  k_drfull<<<dim3(1,6),  256, 0, stream>>>(dr0g3, 0, 1,    0, 6);
  k_fs2 <<<dim3((3600*441+255)/256), 256, 0, stream>>>(drc60, fs2);
  k_psi1<<<dim3((64*441+255)/256),   256, 0, stream>>>(drc24, w1, psi1);
  k_dk  <<<dim3((168*S_L10+255)/256),256, 0, stream>>>(drK2, dk2, S_L10, 10);
  k_dk  <<<dim3((168*S_L5+255)/256), 256, 0, stream>>>(drK3, dk3, S_L5,  5);

  // ---- coeff = x @ FS2 ; psiT = w @ DK (GEMMs) ----
  k_gemm<<<dim3(1,7),   256, 0, stream>>>(x,  fs2, coeff, 8,    441,   3600, 3600LL, 1LL, 441LL,           1LL, 1.0f);
  k_gemm<<<dim3(128,28),256, 0, stream>>>(w2, dk2, psi2T, 8192, S_L10, 168,  168LL,  1LL, (long long)S_L10,1LL, inv_s168);
  k_gemm<<<dim3(512,5), 256, 0, stream>>>(w3, dk3, psi3T, 32768,S_L5,  168,  168LL,  1LL, (long long)S_L5, 1LL, inv_s168);

  // ---- act1: synth (rank-1: coeff x psi1) -> relu*qw -> analysis to lmax 10 ----
  k_syn<20,20,true,64><<<dim3(20,64,8), 256, 0, stream>>>(psi1, coeff, dr20g1, fw1b);
  k_ana<10,20,64>     <<<dim3(64,8),    256, 0, stream>>>(fw1b, dr10g1, h2);
  // ---- so3 linear 2 (64 -> 128) ----
  k_lin<<<dim3(3,42,11), 256, 0, stream>>>(h2, psi2T, h2b, 64, 128, S_L10);
  // ---- act2 ----
  k_syn<10,10,false,128><<<dim3(10,128,8), 256, 0, stream>>>(h2b, nullptr, dr10g2, fw2b);
  k_ana<5,10,128>       <<<dim3(128,8),    256, 0, stream>>>(fw2b, dr5g2, h3);
  // ---- so3 linear 3 (128 -> 256) ----
  k_lin<<<dim3(2,44,6), 256, 0, stream>>>(h3, psi3T, h3b, 128, 256, S_L5);
  // ---- act3 (analysis lmax 0 = weighted sum) ----
  k_syn<5,6,false,256><<<dim3(6,256,8), 256, 0, stream>>>(h3b, nullptr, dr5g3, fw3b);
  k_ana<0,6,256>      <<<dim3(256,8),   256, 0, stream>>>(fw3b, dr0g3, h4);
  // ---- FC head ----
  k_fc<<<dim3(1), 1024, 0, stream>>>(h4, fcw1, fcb1, fcw2, fcb2, out);
}

// Round 2
// 1924.577 us; speedup vs baseline: 1.2991x; 1.2991x over previous
//
#include <hip/hip_runtime.h>

#define PI_D 3.14159265358979323846

constexpr int S_L20 = 12341;  // sum_{l<=20} (2l+1)^2
constexpr int S_L10 = 1771;
constexpr int S_L5  = 286;
constexpr int C_L20 = 441;    // (20+1)^2

__host__ __device__ __forceinline__ int loff(int l) { return l*(4*l*l-1)/3; }

__device__ __forceinline__ int isqrt_dev(int c) {
  int l = (int)sqrtf((float)c);
  while ((l+1)*(l+1) <= c) ++l;
  while (l*l > c) --l;
  return l;
}

// small Wigner-d d^l_{mp,m}(beta); cpw/spw are power tables of cos(beta/2), sin(beta/2)
__device__ double d_small(int l, int mp, int m, const double* cpw, const double* spw, const double* fact) {
  double pref = sqrt(fact[l+mp]*fact[l-mp]*fact[l+m]*fact[l-m]);
  int k0 = max(0, m-mp), k1 = min(l+m, l-mp);
  double val = 0.0;
  for (int k = k0; k <= k1; ++k) {
    double den = fact[l+m-k]*fact[k]*fact[mp-m+k]*fact[l-mp-k];
    double t = (pref/den)*cpw[2*l+m-mp-2*k]*spw[mp-m+2*k];
    val += ((mp-m+k)&1) ? -t : t;
  }
  return val;
}

// real-basis Wigner-d element, row ap, col bp (signed, in [-l,l]).
__device__ double dr_elem(int l, int ap, int bp, const double* cpw, const double* spw, const double* fact) {
  const double IR2 = 0.70710678118654752440;
  if (ap == 0 && bp == 0) return d_small(l,0,0,cpw,spw,fact);
  if (bp == 0) {
    if (ap < 0) return 0.0;
    double sp = (ap&1)? -1.0: 1.0;
    return IR2*(d_small(l,-ap,0,cpw,spw,fact) + sp*d_small(l,ap,0,cpw,spw,fact));
  }
  if (ap == 0) {
    if (bp < 0) return 0.0;
    double sm = (bp&1)? -1.0: 1.0;
    return IR2*(d_small(l,0,-bp,cpw,spw,fact) + sm*d_small(l,0,bp,cpw,spw,fact));
  }
  if (ap > 0 && bp > 0) {
    double sp = (ap&1)?-1.0:1.0, sm = (bp&1)?-1.0:1.0;
    return 0.5*(d_small(l,-ap,-bp,cpw,spw,fact) + sm*d_small(l,-ap,bp,cpw,spw,fact)
              + sp*d_small(l,ap,-bp,cpw,spw,fact) + sp*sm*d_small(l,ap,bp,cpw,spw,fact));
  }
  if (ap < 0 && bp < 0) {
    int mp = -ap, m = -bp;
    double sp = (mp&1)?-1.0:1.0, sm = (m&1)?-1.0:1.0;
    return 0.5*(d_small(l,-mp,-m,cpw,spw,fact) - sm*d_small(l,-mp,m,cpw,spw,fact)
              - sp*d_small(l,mp,-m,cpw,spw,fact) + sp*sm*d_small(l,mp,m,cpw,spw,fact));
  }
  return 0.0;
}

// beta of point p: mode 0: (p+0.5)*pi/gridn ; mode 1: so3 near-identity ; mode 2: s2 near-identity
__device__ double beta_of(int mode, int p, int gridn) {
  if (mode == 0) return (p + 0.5) * (PI_D / gridn);
  if (mode == 1) return (double)(((p >> 3) % 3) + 1) * (PI_D / 24.0);
  return (double)((p % 3) + 1) * (PI_D / 24.0);
}

#define INIT_TABLES(mode, gridn) \
  __shared__ double cpw[44], spw[44], fact[44]; \
  { double beta_ = beta_of(mode, (int)blockIdx.y, gridn); \
    if (threadIdx.x == 0) { double cb_ = cos(beta_*0.5), sb_ = sin(beta_*0.5); \
      cpw[0]=1.0; spw[0]=1.0; fact[0]=1.0; \
      for (int i_=1;i_<44;++i_){cpw[i_]=cpw[i_-1]*cb_; spw[i_]=spw[i_-1]*sb_; fact[i_]=fact[i_-1]*(double)i_;} } \
    __syncthreads(); }

// full real Wigner-d table for one beta set, PRE-SCALED by sqrt(2l+1). out[p][S]
__global__ __launch_bounds__(256) void k_drfull(float* out, int lmax, int S, int mode, int gridn) {
  INIT_TABLES(mode, gridn);
  int p = blockIdx.y;
  int base = blockIdx.x*1024;
  int end = min(S, base + 1024);
  for (int t = base + (int)threadIdx.x; t < end; t += 256) {
    int l = 0; while (l < lmax && t >= loff(l+1)) ++l;
    int j = t - loff(l), d = 2*l+1;
    int a = j/d, b = j%d;
    double v = dr_elem(l, a-l, b-l, cpw, spw, fact) * sqrt(2.0*l+1.0);
    out[(size_t)p*S + t] = (float)v;
  }
}

// m=0 column of real Wigner-d, PRE-SCALED by sqrt(2l+1). out[p][(lmax+1)^2]
__global__ __launch_bounds__(256) void k_drc(float* out, int lmax, int mode, int gridn) {
  INIT_TABLES(mode, gridn);
  int p = blockIdx.y;
  int C = (lmax+1)*(lmax+1);
  for (int t = threadIdx.x; t < C; t += 256) {
    int l = isqrt_dev(t);
    int u = t - l*l - l;
    double v;
    if (u < 0) v = 0.0;
    else if (u == 0) v = d_small(l,0,0,cpw,spw,fact);
    else {
      double sp = (u&1)? -1.0: 1.0;
      v = 0.70710678118654752440*(d_small(l,-u,0,cpw,spw,fact) + sp*d_small(l,u,0,cpw,spw,fact));
    }
    out[(size_t)p*C + t] = (float)(v * sqrt(2.0*l+1.0));
  }
}

// FROM_S2 TRANSPOSED: fs2T[c][ia*60+ib] = qw(ib) * sqrt(2l+1)*(cos(u a)*drc[u] + sin(u a)*drc[-u])
__global__ __launch_bounds__(256) void k_fs2(const float* __restrict__ drc, float* __restrict__ FS2T) {
  int e = blockIdx.x*256 + threadIdx.x;
  if (e >= 441*3600) return;
  int c = e / 3600, k = e % 3600;
  int ia = k / 60, ib = k % 60;
  int l = isqrt_dev(c);
  int u = c - l*l - l;
  double alpha = (double)ia*(2.0*PI_D/60.0);
  double beta  = ((double)ib + 0.5)*(PI_D/60.0);
  double drp = (double)drc[ib*441 + c];
  double drn = (double)drc[ib*441 + (c - 2*u)];
  double val = cos((double)u*alpha)*drp + sin((double)u*alpha)*drn;
  FS2T[e] = (float)(val * (sin(beta)*PI_D/(2.0*60.0*60.0)));
}

// coeff[b][c] = sum_k x[b][k] * fs2T[c][k] ; 441 blocks (one per c), 256 thr
__global__ __launch_bounds__(256) void k_coeff(const float* __restrict__ x, const float* __restrict__ fs2T,
                                               float* __restrict__ coeff) {
  int c = blockIdx.x;
  int tid = threadIdx.x;
  float acc[8] = {};
  const float* fr = fs2T + (size_t)c*3600;
  for (int k = tid; k < 3600; k += 256) {
    float w = fr[k];
#pragma unroll
    for (int b = 0; b < 8; ++b) acc[b] += w * x[b*3600 + k];
  }
  __shared__ float red[8][256];
#pragma unroll
  for (int b = 0; b < 8; ++b) red[b][tid] = acc[b];
  __syncthreads();
  for (int s = 128; s > 0; s >>= 1) {
    if (tid < s) {
#pragma unroll
      for (int b = 0; b < 8; ++b) red[b][tid] += red[b][tid+s];
    }
    __syncthreads();
  }
  if (tid < 8) coeff[tid*441 + c] = red[tid][0];
}

// psi1[o][c] = (1/sqrt24) * sum_p Y_K[p,c] * w1[o,p]
__global__ __launch_bounds__(256) void k_psi1(const float* __restrict__ drc24, const float* __restrict__ w1,
                                              float* __restrict__ psi1) {
  int e = blockIdx.x*256 + threadIdx.x;
  if (e >= 64*441) return;
  int o = e / 441, c = e % 441;
  int l = isqrt_dev(c);
  int u = c - l*l - l;
  float acc = 0.f;
  for (int p = 0; p < 24; ++p) {
    double alpha = (double)(p/3)*(PI_D/4.0);
    double y = cos((double)u*alpha)*(double)drc24[p*441+c] + sin((double)u*alpha)*(double)drc24[p*441 + (c-2*u)];
    acc += (float)y * w1[o*24 + p];
  }
  psi1[e] = acc * 0.20412414523193150818f;
}

// D_K (flat wigner at near-identity so3 points) from pre-scaled dr table
__global__ __launch_bounds__(256) void k_dk(const float* __restrict__ drk, float* __restrict__ DK, int S, int lmax) {
  int e = blockIdx.x*256 + threadIdx.x;
  if (e >= 168*S) return;
  int n = e / S, idx = e % S;
  int l = 0; while (l < lmax && idx >= loff(l+1)) ++l;
  int j = idx - loff(l), d = 2*l+1;
  int iu = j/d, im = j%d;
  int u = iu - l, m = im - l;
  int i3 = n/24, k3 = n%8;
  double alpha = (double)i3*(2.0*PI_D/7.0);
  double gamma = (-2.0*PI_D + (double)k3*(4.0*PI_D/7.0)) - alpha;
  const float* drb = drk + (size_t)n*S + loff(l);
  double d_um   = drb[iu*d+im];
  double d_umn  = drb[iu*d + (d-1-im)];
  double d_unm  = drb[(d-1-iu)*d + im];
  double d_unmn = drb[(d-1-iu)*d + (d-1-im)];
  double cA = cos((double)u*alpha), sA = sin((double)u*alpha);
  double cG = cos((double)m*gamma), sG = sin((double)m*gamma);
  DK[e] = (float)(cA*(cG*d_um - sG*d_umn) + sA*(cG*d_unm - sG*d_unmn));
}

// generic strided fp32 GEMM: C[M][N] = alpha * A(r,k) B(k,c)
__global__ __launch_bounds__(256) void k_gemm(const float* __restrict__ A, const float* __restrict__ B,
                                              float* __restrict__ C, int M, int N, int K,
                                              long long ars, long long aks, long long bks, long long bcs,
                                              float alpha) {
  __shared__ float As[16][65], Bs[16][65];
  int tm = blockIdx.x*64, tn = blockIdx.y*64;
  int tid = threadIdx.x, ty = tid/16, tx = tid%16;
  float acc[4][4] = {};
  for (int k0 = 0; k0 < K; k0 += 16) {
    for (int t = tid; t < 1024; t += 256) {
      int rr = t % 64, kk = t / 64;
      int r = tm + rr, k = k0 + kk;
      float v = 0.f;
      if (r < M && k < K) v = A[(long long)r*ars + (long long)k*aks];
      As[kk][rr] = v;
    }
    for (int t = tid; t < 1024; t += 256) {
      int cc = t % 64, kk = t / 64;
      int c = tn + cc, k = k0 + kk;
      float v = 0.f;
      if (c < N && k < K) v = B[(long long)k*bks + (long long)c*bcs];
      Bs[kk][cc] = v;
    }
    __syncthreads();
#pragma unroll
    for (int kk = 0; kk < 16; ++kk) {
      float av[4], bv[4];
#pragma unroll
      for (int q = 0; q < 4; ++q) { av[q] = As[kk][ty*4+q]; bv[q] = Bs[kk][tx*4+q]; }
#pragma unroll
      for (int q = 0; q < 4; ++q)
#pragma unroll
        for (int r2 = 0; r2 < 4; ++r2) acc[q][r2] += av[q]*bv[r2];
    }
    __syncthreads();
  }
  for (int q = 0; q < 4; ++q) {
    int r = tm + ty*4 + q; if (r >= M) continue;
    for (int r2 = 0; r2 < 4; ++r2) {
      int c = tn + tx*4 + r2; if (c >= N) continue;
      C[(size_t)r*N + c] = alpha*acc[q][r2];
    }
  }
}

// per-l block linear: out[b,o,l,v,m] = 1/sqrt(FI*d) * sum_{i,u} hin[b,i,l,u,m] * psiT[(i*FO+o)][l,u,v]
__global__ __launch_bounds__(256) void k_lin(const float* __restrict__ hin, const float* __restrict__ psiT,
                                             float* __restrict__ hout, int FI, int FO, int S) {
  int l = blockIdx.z;
  int d = 2*l+1, off = loff(l);
  int Ml = 8*d, Nl = FO*d, Kl = FI*d;
  int tm = blockIdx.x*64, tn = blockIdx.y*64;
  if (tm >= Ml || tn >= Nl) return;
  float alpha = 1.0f/sqrtf((float)(FI*d));
  __shared__ float As[16][65], Bs[16][65];
  int tid = threadIdx.x, ty = tid/16, tx = tid%16;
  float acc[4][4] = {};
  for (int k0 = 0; k0 < Kl; k0 += 16) {
    for (int t = tid; t < 1024; t += 256) {
      int rr = t % 64, kk = t / 64;
      int r = tm + rr, k = k0 + kk;
      float v = 0.f;
      if (r < Ml && k < Kl) {
        int bb = r / d, m = r - bb*d;
        int i  = k / d, u = k - i*d;
        v = hin[((size_t)(bb*FI + i))*S + off + u*d + m];
      }
      As[kk][rr] = v;
    }
    for (int t = tid; t < 1024; t += 256) {
      int cc = t % 64, kk = t / 64;
      int c = tn + cc, k = k0 + kk;
      float v = 0.f;
      if (c < Nl && k < Kl) {
        int o = c / d, vv = c - o*d;
        int i = k / d, u  = k - i*d;
        v = psiT[((size_t)(i*FO + o))*S + off + u*d + vv];
      }
      Bs[kk][cc] = v;
    }
    __syncthreads();
#pragma unroll
    for (int kk = 0; kk < 16; ++kk) {
      float av[4], bv[4];
#pragma unroll
      for (int q = 0; q < 4; ++q) { av[q] = As[kk][ty*4+q]; bv[q] = Bs[kk][tx*4+q]; }
#pragma unroll
      for (int q = 0; q < 4; ++q)
#pragma unroll
        for (int r2 = 0; r2 < 4; ++r2) acc[q][r2] += av[q]*bv[r2];
    }
    __syncthreads();
  }
  for (int q = 0; q < 4; ++q) {
    int r = tm + ty*4 + q; if (r >= Ml) continue;
    int bb = r / d, m = r - bb*d;
    for (int r2 = 0; r2 < 4; ++r2) {
      int c = tn + tx*4 + r2; if (c >= Nl) continue;
      int o = c / d, vv = c - o*d;
      hout[((size_t)(bb*FO + o))*S + off + vv*d + m] = alpha*acc[q][r2];
    }
  }
}

// factorized SO(3) grid synthesis + relu + quad-weight. fw[b][f][ib][ia][ig]
template<int L, int NG, bool RANK1, int F>
__global__ __launch_bounds__(256) void k_syn(const float* __restrict__ hin, const float* __restrict__ coeff,
                                             const float* __restrict__ drg, float* __restrict__ fw) {
  constexpr int U = 2*L+1;
  constexpr int S = (L+1)*(2*L+1)*(2*L+3)/3;
  constexpr int HSZ = RANK1 ? 2*C_L20 : S;
  __shared__ float P[U*U], Q1[U*U], Q2[U*U], Q3[U*U];
  __shared__ float Rc[U*NG], Rs[U*NG];
  __shared__ float cg[NG*U], sg[NG*U];
  __shared__ float hrow[HSZ];
  int ib = blockIdx.x, f = blockIdx.y, b = blockIdx.z;
  int tid = threadIdx.x;
  if (RANK1) {
    for (int t = tid; t < C_L20; t += 256) {
      hrow[t]          = hin[f*C_L20 + t];
      hrow[C_L20 + t]  = coeff[b*C_L20 + t];
    }
  } else {
    for (int t = tid; t < S; t += 256) hrow[t] = hin[((size_t)b*F + f)*S + t];
  }
  for (int t = tid; t < NG*U; t += 256) {
    int ig = t / U, mu = t % U - L;
    double ang = (double)mu * (double)ig * (2.0*PI_D/(double)NG);
    cg[t] = (float)cos(ang); sg[t] = (float)sin(ang);
  }
  __syncthreads();
  for (int t = tid; t < U*U; t += 256) {
    int uu = t / U, mm = t % U;
    int au = (uu >= L) ? uu - L : L - uu;
    int am = (mm >= L) ? mm - L : L - mm;
    int lmin = max(au, am);
    float p = 0.f, q1 = 0.f, q2 = 0.f, q3 = 0.f;
    for (int l = lmin; l <= L; ++l) {
      int d = 2*l+1;
      int iu = uu - (L - l), im = mm - (L - l);
      float drv = drg[(size_t)ib*S + loff(l) + iu*d + im];
      if (RANK1) {
        int cb = l*l;
        float hu  = hrow[cb + iu],          hun = hrow[cb + (d-1-iu)];
        float hm  = hrow[C_L20 + cb + im],  hmn = hrow[C_L20 + cb + (d-1-im)];
        p  += drv*hu*hm;  q1 += drv*hu*hmn;  q2 += drv*hun*hm;  q3 += drv*hun*hmn;
      } else {
        int o = loff(l);
        p  += drv*hrow[o + iu*d + im];
        q1 += drv*hrow[o + iu*d + (d-1-im)];
        q2 += drv*hrow[o + (d-1-iu)*d + im];
        q3 += drv*hrow[o + (d-1-iu)*d + (d-1-im)];
      }
    }
    P[t]=p; Q1[t]=q1; Q2[t]=q2; Q3[t]=q3;
  }
  __syncthreads();
  for (int t = tid; t < U*NG; t += 256) {
    int uu = t / NG, ig = t % NG;
    float rc = 0.f, rs = 0.f;
    for (int mm = 0; mm < U; ++mm) {
      float c = cg[ig*U+mm], s = sg[ig*U+mm];
      int pi = uu*U+mm;
      rc += c*P[pi]  + s*Q1[pi];
      rs += c*Q2[pi] + s*Q3[pi];
    }
    Rc[t]=rc; Rs[t]=rs;
  }
  __syncthreads();
  double beta = ((double)ib + 0.5) * (PI_D / (double)NG);
  float qwv = (float)(sin(beta) * PI_D / (2.0*(double)NG*(double)NG*(double)NG));
  size_t obase = (((size_t)b*F + f)*NG + ib)*(size_t)(NG*NG);
  for (int t = tid; t < NG*NG; t += 256) {
    int ia = t / NG, ig = t % NG;
    float acc = 0.f;
    for (int uu = 0; uu < U; ++uu)
      acc += cg[ia*U+uu]*Rc[uu*NG+ig] - sg[ia*U+uu]*Rs[uu*NG+ig];
    fw[obase + t] = fmaxf(acc, 0.0f) * qwv;
  }
}

// factorized SO(3) grid analysis to lmax LO. hout[b][f][SO]
template<int LO, int NG, int F>
__global__ __launch_bounds__(256) void k_ana(const float* __restrict__ fw, const float* __restrict__ drg,
                                             float* __restrict__ hout) {
  constexpr int UO = 2*LO+1;
  constexpr int SO = (LO+1)*(2*LO+1)*(2*LO+3)/3;
  __shared__ float hacc[SO];
  __shared__ float fws[NG*NG];
  __shared__ float Fc[UO*NG], Fs[UO*NG];
  __shared__ float Gcc[UO*UO], Gcs[UO*UO], Gsc[UO*UO], Gss[UO*UO];
  __shared__ float cg[NG*UO], sg[NG*UO];
  int f = blockIdx.x, b = blockIdx.y, tid = threadIdx.x;
  for (int t = tid; t < SO; t += 256) hacc[t] = 0.0f;
  for (int t = tid; t < NG*UO; t += 256) {
    int ig = t / UO, mu = t % UO - LO;
    double ang = (double)mu * (double)ig * (2.0*PI_D/(double)NG);
    cg[t] = (float)cos(ang); sg[t] = (float)sin(ang);
  }
  __syncthreads();
  for (int ib = 0; ib < NG; ++ib) {
    size_t base = (((size_t)b*F + f)*NG + ib)*(size_t)(NG*NG);
    for (int t = tid; t < NG*NG; t += 256) fws[t] = fw[base + t];
    __syncthreads();
    for (int t = tid; t < UO*NG; t += 256) {
      int uu = t / NG, ig = t % NG;
      float fc = 0.f, fs = 0.f;
      for (int ia = 0; ia < NG; ++ia) {
        float v = fws[ia*NG + ig];
        fc += cg[ia*UO + uu]*v;
        fs += sg[ia*UO + uu]*v;
      }
      Fc[t]=fc; Fs[t]=fs;
    }
    __syncthreads();
    for (int t = tid; t < UO*UO; t += 256) {
      int uu = t/UO, mm = t%UO;
      float gcc=0.f,gcs=0.f,gsc=0.f,gss=0.f;
      for (int ig = 0; ig < NG; ++ig) {
        float c = cg[ig*UO+mm], s = sg[ig*UO+mm];
        float fc = Fc[uu*NG+ig], fs = Fs[uu*NG+ig];
        gcc += c*fc; gcs += s*fc; gsc += c*fs; gss += s*fs;
      }
      Gcc[t]=gcc; Gcs[t]=gcs; Gsc[t]=gsc; Gss[t]=gss;
    }
    __syncthreads();
    for (int t = tid; t < SO; t += 256) {
      int l = 0; while (l < LO && t >= loff(l+1)) ++l;
      int j = t - loff(l), d = 2*l+1;
      int iu = j / d, im = j % d;
      int uu = iu + (LO - l), mm = im + (LO - l);
      const float* drb = drg + (size_t)ib*SO + loff(l);
      hacc[t] += Gcc[uu*UO+mm]*drb[iu*d+im]
               - Gcs[uu*UO+mm]*drb[iu*d+(d-1-im)]
               + Gsc[uu*UO+mm]*drb[(d-1-iu)*d+im]
               - Gss[uu*UO+mm]*drb[(d-1-iu)*d+(d-1-im)];
    }
    __syncthreads();
  }
  for (int t = tid; t < SO; t += 256) hout[((size_t)b*F + f)*SO + t] = hacc[t];
}

// final two FC layers. one block, 1024 threads.
__global__ __launch_bounds__(1024) void k_fc(const float* __restrict__ h4, const float* __restrict__ w1,
                                             const float* __restrict__ b1, const float* __restrict__ w2,
                                             const float* __restrict__ b2, float* __restrict__ out) {
  __shared__ float t1[1024];
  int tid = threadIdx.x;
  {
    int b = tid >> 7, j = tid & 127;
    float a = b1[j];
    const float* hr = h4 + b*256;
    for (int k = 0; k < 256; ++k) a += hr[k]*w1[k*128 + j];
    t1[tid] = fmaxf(a, 0.f);
  }
  __syncthreads();
  if (tid < 80) {
    int b = tid / 10, j = tid % 10;
    float a = b2[j];
    for (int k = 0; k < 128; ++k) a += t1[b*128 + k]*w2[k*10 + j];
    out[b*10 + j] = a;
  }
}

extern "C" void kernel_launch(void* const* d_in, const int* in_sizes, int n_in,
                              void* d_out, int out_size, void* d_ws, size_t ws_size,
                              hipStream_t stream) {
  const float* x    = (const float*)d_in[0];
  const float* w1   = (const float*)d_in[1];
  const float* w2   = (const float*)d_in[2];
  const float* w3   = (const float*)d_in[3];
  const float* fcw1 = (const float*)d_in[4];
  const float* fcb1 = (const float*)d_in[5];
  const float* fcw2 = (const float*)d_in[6];
  const float* fcb2 = (const float*)d_in[7];
  float* out = (float*)d_out;

  float* base = (float*)d_ws;
  size_t off = 0;
  auto alloc = [&](size_t n) -> float* { float* p = base + off; off += (n + 63) & ~(size_t)63; return p; };

  float* drc60  = alloc((size_t)60*441);
  float* drc24  = alloc((size_t)24*441);
  float* fs2T   = alloc((size_t)441*3600);
  float* psi1   = alloc((size_t)64*441);
  float* coeff  = alloc((size_t)8*441);
  float* drK2   = alloc((size_t)168*S_L10);
  float* drK3   = alloc((size_t)168*S_L5);
  float* dk2    = alloc((size_t)168*S_L10);
  float* dk3    = alloc((size_t)168*S_L5);
  float* psi2T  = alloc((size_t)8192*S_L10);
  float* psi3T  = alloc((size_t)32768*S_L5);
  float* dr20g1 = alloc((size_t)20*S_L20);
  float* dr10g1 = alloc((size_t)20*S_L10);
  float* dr10g2 = alloc((size_t)10*S_L10);
  float* dr5g2  = alloc((size_t)10*S_L5);
  float* dr5g3  = alloc((size_t)6*S_L5);
  float* dr0g3  = alloc(6);
  float* fw1b   = alloc((size_t)8*64*8000);
  float* h2     = alloc((size_t)8*64*S_L10);
  float* h2b    = alloc((size_t)8*128*S_L10);
  float* fw2b   = alloc((size_t)8*128*1000);
  float* h3     = alloc((size_t)8*128*S_L5);
  float* h3b    = alloc((size_t)8*256*S_L5);
  float* fw3b   = alloc((size_t)8*256*216);
  float* h4     = alloc((size_t)8*256);
  if (off * sizeof(float) > ws_size) return;

  const float inv_s168 = 0.07715167498104595f;  // 1/sqrt(168)

  // ---- constant-table generation (device, fp64, every call: graph-replay safe) ----
  k_drc<<<dim3(1,60), 256, 0, stream>>>(drc60, 20, 0, 60);
  k_drc<<<dim3(1,24), 256, 0, stream>>>(drc24, 20, 2, 0);
  k_drfull<<<dim3((S_L10+1023)/1024,168), 256, 0, stream>>>(drK2, 10, S_L10, 1, 0);
  k_drfull<<<dim3(1,168),                 256, 0, stream>>>(drK3,  5, S_L5,  1, 0);
  k_drfull<<<dim3((S_L20+1023)/1024,20),  256, 0, stream>>>(dr20g1, 20, S_L20, 0, 20);
  k_drfull<<<dim3((S_L10+1023)/1024,20),  256, 0, stream>>>(dr10g1, 10, S_L10, 0, 20);
  k_drfull<<<dim3((S_L10+1023)/1024,10),  256, 0, stream>>>(dr10g2, 10, S_L10, 0, 10);
  k_drfull<<<dim3(1,10), 256, 0, stream>>>(dr5g2, 5, S_L5, 0, 10);
  k_drfull<<<dim3(1,6),  256, 0, stream>>>(dr5g3, 5, S_L5, 0, 6);
  k_drfull<<<dim3(1,6),  256, 0, stream>>>(dr0g3, 0, 1,    0, 6);
  k_fs2 <<<dim3((441*3600+255)/256), 256, 0, stream>>>(drc60, fs2T);
  k_psi1<<<dim3((64*441+255)/256),   256, 0, stream>>>(drc24, w1, psi1);
  k_dk  <<<dim3((168*S_L10+255)/256),256, 0, stream>>>(drK2, dk2, S_L10, 10);
  k_dk  <<<dim3((168*S_L5+255)/256), 256, 0, stream>>>(drK3, dk3, S_L5,  5);

  // ---- coeff = x @ FS2 (reduction kernel) ; psiT = w @ DK (GEMMs) ----
  k_coeff<<<dim3(441), 256, 0, stream>>>(x, fs2T, coeff);
  k_gemm<<<dim3(128,28),256, 0, stream>>>(w2, dk2, psi2T, 8192, S_L10, 168,  168LL,  1LL, (long long)S_L10,1LL, inv_s168);
  k_gemm<<<dim3(512,5), 256, 0, stream>>>(w3, dk3, psi3T, 32768,S_L5,  168,  168LL,  1LL, (long long)S_L5, 1LL, inv_s168);

  // ---- act1: synth (rank-1: coeff x psi1) -> relu*qw -> analysis to lmax 10 ----
  k_syn<20,20,true,64><<<dim3(20,64,8), 256, 0, stream>>>(psi1, coeff, dr20g1, fw1b);
  k_ana<10,20,64>     <<<dim3(64,8),    256, 0, stream>>>(fw1b, dr10g1, h2);
  // ---- so3 linear 2 (64 -> 128) ----
  k_lin<<<dim3(3,42,11), 256, 0, stream>>>(h2, psi2T, h2b, 64, 128, S_L10);
  // ---- act2 ----
  k_syn<10,10,false,128><<<dim3(10,128,8), 256, 0, stream>>>(h2b, nullptr, dr10g2, fw2b);
  k_ana<5,10,128>       <<<dim3(128,8),    256, 0, stream>>>(fw2b, dr5g2, h3);
  // ---- so3 linear 3 (128 -> 256) ----
  k_lin<<<dim3(2,44,6), 256, 0, stream>>>(h3, psi3T, h3b, 128, 256, S_L5);
  // ---- act3 (analysis lmax 0 = weighted sum) ----
  k_syn<5,6,false,256><<<dim3(6,256,8), 256, 0, stream>>>(h3b, nullptr, dr5g3, fw3b);
  k_ana<0,6,256>      <<<dim3(256,8),   256, 0, stream>>>(fw3b, dr0g3, h4);
  // ---- FC head ----
  k_fc<<<dim3(1), 1024, 0, stream>>>(h4, fcw1, fcb1, fcw2, fcb2, out);
}